// Round 14
// baseline (1619.445 us; speedup 1.0000x reference)
//
#include <hip/hip_runtime.h>
#include <math.h>

#define BATCH  256
#define CODE   64
#define HID    256
#define TSTEPS 640     // 512 encoder + 128 decoder steps

// ---- workspace layout (float offsets)
#define OFF_A0   0          // fp16 [64rt][10f][64lane][8] = 327680 halfs = 163840 floats
#define OFF_A1   163840     // fp16 [64rt][16f][64lane][8] = 524288 halfs = 262144 floats
#define OFF_BP0  425984     // [1024] permuted fused bias layer0
#define OFF_BP1  427008     // [1024]
#define OFF_HEX  428032     // [2buf][16grp][16wgsrc][2layer][4uq][16b] x 16B = 1MB = 262144 floats
#define WS_FLOATS (OFF_HEX + 262144)

typedef __attribute__((ext_vector_type(8))) short    short8;
typedef __attribute__((ext_vector_type(8))) _Float16 half8;
typedef __attribute__((ext_vector_type(4))) float    f32x4;
typedef __attribute__((ext_vector_type(4))) unsigned int u32x4;
typedef unsigned long long u64;

__device__ __forceinline__ f32x4 mfma16h(half8 a, half8 b, f32x4 c) {
  return __builtin_amdgcn_mfma_f32_16x16x32_f16(a, b, c, 0, 0, 0);
}
__device__ __forceinline__ unsigned short f2h(float f) {
  _Float16 h = (_Float16)f;                  // RNE
  return __builtin_bit_cast(unsigned short, h);
}
__device__ __forceinline__ float h2f(unsigned short u) {
  return (float)__builtin_bit_cast(_Float16, u);
}
#define LOG2E 1.4426950408889634f
__device__ __forceinline__ float sigm(float x) {
  return __builtin_amdgcn_rcpf(1.0f + __builtin_amdgcn_exp2f(-x * LOG2E));
}
__device__ __forceinline__ float tanh_f(float x) {
  return 1.0f - 2.0f * __builtin_amdgcn_rcpf(1.0f + __builtin_amdgcn_exp2f(x * (2.0f * LOG2E)));
}

// ---- one-time weight swizzle into MFMA fragment order, single fp16 plane.
__global__ void setup_kernel(const float* __restrict__ Wih0, const float* __restrict__ Whh0,
                             const float* __restrict__ bih0, const float* __restrict__ bhh0,
                             const float* __restrict__ Wih1, const float* __restrict__ Whh1,
                             const float* __restrict__ bih1, const float* __restrict__ bhh1,
                             float* __restrict__ ws) {
  int i = blockIdx.x * 256 + threadIdx.x;
  unsigned short* u = (unsigned short*)ws;
  if (i < 327680) {        // layer0: K = 320 (64 x | 256 h0)
    int rt = i / 5120, r = i % 5120;
    int f = r >> 9, l = (r >> 3) & 63, j = r & 7;
    int p = rt * 16 + (l & 15);
    int orig = (p & 3) * 256 + (p >> 2);
    int k = f * 32 + ((l >> 4) << 3) + j;
    float w = (k < 64) ? Wih0[orig * 64 + k] : Whh0[orig * 256 + k - 64];
    u[OFF_A0 * 2 + rt * 5120 + f * 512 + l * 8 + j] = f2h(w);
    return;
  }
  i -= 327680;
  if (i < 524288) {        // layer1: K = 512 (256 h0 | 256 h1)
    int rt = i >> 13, r = i & 8191;
    int f = r >> 9, l = (r >> 3) & 63, j = r & 7;
    int p = rt * 16 + (l & 15);
    int orig = (p & 3) * 256 + (p >> 2);
    int k = f * 32 + ((l >> 4) << 3) + j;
    float w = (k < 256) ? Wih1[orig * 256 + k] : Whh1[orig * 256 + k - 256];
    u[OFF_A1 * 2 + rt * 8192 + f * 512 + l * 8 + j] = f2h(w);
    return;
  }
  i -= 524288;
  if (i < 2048) {
    int layer = i >> 10, p = i & 1023;
    int orig = (p & 3) * 256 + (p >> 2);
    ws[OFF_BP0 + i] = layer ? (bih1[orig] + bhh1[orig]) : (bih0[orig] + bhh0[orig]);
  }
}

// quantum byte offset: [buf][grp][wgsrc][layer][uq][b] x 16B
// quantum = {tagA, 2 units fp16, 2 units fp16, tagB}
__device__ __forceinline__ size_t qoff(int buf, int grp, int wgsrc, int layer, int uq, int b) {
  return (size_t)(((((buf * 16 + grp) * 16 + wgsrc) * 2 + layer) * 4 + uq) * 16 + b) * 16u;
}

// ---- persistent MFMA LSTM, tagged-quantum sync (R8/R13 protocol).
// 256 WGs x 512 thr; 16 groups x 16 WGs. waves 0-3: layer0 (step T);
// waves 4-7: layer1 (step T-1).
// R14: single-plane fp16 weights+activations (halves MFMA count, improves
// accuracy vs bf16 activations); s_sleep(1) backoff on failed poll attempts.
__global__ __launch_bounds__(512, 2) void lstm_mfma(
    const float* __restrict__ x, const float* __restrict__ targets,
    const float* __restrict__ fcW, const float* __restrict__ fcb,
    float* __restrict__ ws, float* __restrict__ out) {
  __shared__ __align__(16) short Bx[2][64][8];        // x frags (fp16 bits)
  __shared__ __align__(16) short Bh0[8][64][8];       // h0 frags
  __shared__ __align__(16) short Bh1[8][64][8];       // h1 frags (FC reads too)
  __shared__ float fcw_s[64 * 257];

  const int t = threadIdx.x;
  const int blk = blockIdx.x;
  const int xcd = blk & 7, slot = blk >> 3;
  const int grp = xcd * 2 + (slot >> 4);   // 0..15
  const int wg  = slot & 15;               // 0..15

  const int w = t >> 6, l = t & 63, wl = w & 3;
  const bool isL0 = (w < 4);
  const int rt = wg * 4 + wl;

  char* hexb = (char*)(ws + OFF_HEX);

  for (int idx = t; idx < 64 * 256; idx += 512)
    fcw_s[(idx >> 8) * 257 + (idx & 255)] = fcW[idx];

  // ---- register-resident A fragments (single fp16 plane)
  half8 Af[16];
  const unsigned short* u16w = (const unsigned short*)ws;
  if (isL0) {
    const unsigned short* Ab = u16w + OFF_A0 * 2 + rt * 5120;
#pragma unroll
    for (int f = 0; f < 10; ++f)
      Af[f] = *(const half8*)(Ab + f * 512 + l * 8);
  } else {
    const unsigned short* Ab = u16w + OFF_A1 * 2 + rt * 8192;
#pragma unroll
    for (int f = 0; f < 16; ++f)
      Af[f] = *(const half8*)(Ab + f * 512 + l * 8);
  }
  const f32x4 bias = *(const f32x4*)(ws + (isL0 ? OFF_BP0 : OFF_BP1) + rt * 16 + ((l >> 4) << 2));
  float cst = 0.0f;

  const int col = l & 15;
  const int k0 = (w << 5) + ((l >> 4) << 3);
  const int wgsrc = k0 >> 4, uq0 = (k0 & 15) >> 2;   // uq0 in {0,2}

  // FC roles: waves 3 and 5; 2 lanes per output (k-halves), 32 outputs/wave.
  const int fc_code  = 4 * wg + ((w == 5) ? 2 : 0) + (l & 1);  // global code
  const int fc_b     = (l >> 1) & 15;                          // batch in group
  const int fc_khalf = l >> 5;                                 // 0: k<128, 1: k>=128
  const float fcb_r  = fcb[fc_code];

  float4 xr0, xr1;
  auto load_x = [&](int s) {
    if (w < 2 && s < TSTEPS) {
      const float* src;
      if (s <= 512) {
        int ss = (s < 512) ? s : 511;
        src = x + ((size_t)(grp * 16 + col) * 512 + ss) * 64 + k0;
      } else {
        src = targets + ((size_t)(grp * 16 + col) * 128 + (s - 513)) * 64 + k0;
      }
      xr0 = *(const float4*)src;
      xr1 = *(const float4*)(src + 4);
    }
  };
  auto put_x = [&]() {
    if (w < 2) {
      short8 v;
      v[0] = (short)f2h(xr0.x); v[1] = (short)f2h(xr0.y);
      v[2] = (short)f2h(xr0.z); v[3] = (short)f2h(xr0.w);
      v[4] = (short)f2h(xr1.x); v[5] = (short)f2h(xr1.y);
      v[6] = (short)f2h(xr1.z); v[7] = (short)f2h(xr1.w);
      *(short8*)Bx[w][l] = v;
    }
  };

  // ---- prologue: zero h frags, stage x(0)
  *(u32x4*)&Bh0[w][l][0] = u32x4{0, 0, 0, 0};
  *(u32x4*)&Bh1[w][l][0] = u32x4{0, 0, 0, 0};
  load_x(0); put_x();
  __syncthreads();

  u32x4 q00, q01, q10, q11;   // staged tagged quanta (regs across bar2)

  for (int T = 0; T <= TSTEPS + 1; ++T) {
    // ---- compute phase (single fp16 plane, 2 chains)
    float hh = 0.0f;
    const bool act = isL0 ? (T < TSTEPS) : (T >= 1 && T <= TSTEPS);
    if (act) {
      f32x4 a0 = {0.f,0.f,0.f,0.f}, a1 = {0.f,0.f,0.f,0.f};
      if (isL0) {
        a0 = mfma16h(Af[0], *(const half8*)Bx[0][l], a0);
        a1 = mfma16h(Af[1], *(const half8*)Bx[1][l], a1);
#pragma unroll
        for (int f = 2; f < 10; ++f) {
          half8 b = *(const half8*)Bh0[f - 2][l];
          if (f & 1) a1 = mfma16h(Af[f], b, a1);
          else       a0 = mfma16h(Af[f], b, a0);
        }
      } else {
#pragma unroll
        for (int f = 0; f < 8; ++f) {
          half8 b = *(const half8*)Bh0[f][l];
          if (f & 1) a1 = mfma16h(Af[f], b, a1);
          else       a0 = mfma16h(Af[f], b, a0);
        }
#pragma unroll
        for (int f = 8; f < 16; ++f) {
          half8 b = *(const half8*)Bh1[f - 8][l];
          if (f & 1) a1 = mfma16h(Af[f], b, a1);
          else       a0 = mfma16h(Af[f], b, a0);
        }
      }
      f32x4 s = a0 + a1 + bias;
      cst = sigm(s.y) * cst + sigm(s.x) * tanh_f(s.z);
      hh = sigm(s.w) * tanh_f(cst);
    }

    const unsigned tag = (unsigned)(T + 1);

    // ---- export: shfl-pack 4 units x batch, single tagged 16B store (no drain)
    if (T <= TSTEPS) {
      unsigned bh = f2h(hh);
      unsigned v0 = __shfl((int)bh, (l & 15));
      unsigned v1 = __shfl((int)bh, 16 + (l & 15));
      unsigned v2 = __shfl((int)bh, 32 + (l & 15));
      unsigned v3 = __shfl((int)bh, 48 + (l & 15));
      if (l < 16) {
        u32x4 ex = {tag, v0 | (v1 << 16), v2 | (v3 << 16), tag};
        char* pe = hexb + qoff(T & 1, grp, wg, isL0 ? 0 : 1, wl, l);
        asm volatile("global_store_dwordx4 %0, %1, off sc0 sc1"
                     :: "v"(pe), "v"(ex) : "memory");
      }
    }

    if (w < 2 && (T + 1) < TSTEPS) load_x(T + 1);   // x prefetch into regs

    // ---- FC projection: waves 3 & 5, 2 lanes/output (k-halves), 4 chains.
    if ((w == 3 || w == 5) && T >= 514) {
      int d = T - 514;
      float a0 = 0.f, a1 = 0.f, a2 = 0.f, a3 = 0.f;
      const float* fw = fcw_s + fc_code * 257 + fc_khalf * 128;
#pragma unroll
      for (int kq = 0; kq < 4; ++kq) {
        int f = fc_khalf * 4 + kq;
        short8 h0v = *(const short8*)Bh1[f][0 * 16 + fc_b];
        short8 h1v = *(const short8*)Bh1[f][1 * 16 + fc_b];
        short8 h2v = *(const short8*)Bh1[f][2 * 16 + fc_b];
        short8 h3v = *(const short8*)Bh1[f][3 * 16 + fc_b];
#pragma unroll
        for (int j = 0; j < 8; ++j) {
          a0 = fmaf(fw[kq * 32 + j],      h2f((unsigned short)h0v[j]), a0);
          a1 = fmaf(fw[kq * 32 + 8 + j],  h2f((unsigned short)h1v[j]), a1);
          a2 = fmaf(fw[kq * 32 + 16 + j], h2f((unsigned short)h2v[j]), a2);
          a3 = fmaf(fw[kq * 32 + 24 + j], h2f((unsigned short)h3v[j]), a3);
        }
      }
      float acc = (a0 + a1) + (a2 + a3);
      acc += __shfl_xor(acc, 32);     // combine k-halves (l <-> l^32)
      if (l < 32)
        __builtin_nontemporal_store(acc + fcb_r,
            &out[(size_t)(grp * 16 + fc_b) * 8192 + d * 64 + fc_code]);
    }

    // ---- poll: re-load own 4 quanta until both tags match (fused detect+data)
    if (T <= TSTEPS) {
      char* pb = hexb + qoff(T & 1, grp, wgsrc, 0, uq0, col);
      while (true) {
        asm volatile(
            "global_load_dwordx4 %0, %4, off sc0 sc1\n\t"
            "global_load_dwordx4 %1, %4, off offset:256 sc0 sc1\n\t"
            "global_load_dwordx4 %2, %4, off offset:1024 sc0 sc1\n\t"
            "global_load_dwordx4 %3, %4, off offset:1280 sc0 sc1\n\t"
            "s_waitcnt vmcnt(0)"
            : "=v"(q00), "=v"(q01), "=v"(q10), "=v"(q11)
            : "v"(pb) : "memory");
        bool ok = (q00.x == tag) & (q00.w == tag) & (q01.x == tag) & (q01.w == tag) &
                  (q10.x == tag) & (q10.w == tag) & (q11.x == tag) & (q11.w == tag);
        if (__all(ok)) break;
        __builtin_amdgcn_s_sleep(1);   // backoff only after a miss
      }
    }
    __syncthreads();                                   // bar2: compute-reads done

    // ---- LDS write phase: staged quanta -> frags for tick T+1
    if (T <= TSTEPS) {
      *(u32x4*)&Bh0[w][l][0] = u32x4{q00.y, q00.z, q01.y, q01.z};
      *(u32x4*)&Bh1[w][l][0] = u32x4{q10.y, q10.z, q11.y, q11.z};
      if ((T + 1) < TSTEPS) put_x();
    }
    __syncthreads();                                   // bar1: frags ready
  }
}

extern "C" void kernel_launch(void* const* d_in, const int* in_sizes, int n_in,
                              void* d_out, int out_size, void* d_ws, size_t ws_size,
                              hipStream_t stream) {
  const float* x       = (const float*)d_in[0];
  const float* targets = (const float*)d_in[1];
  const float* Wih0    = (const float*)d_in[2];
  const float* Whh0    = (const float*)d_in[3];
  const float* bih0    = (const float*)d_in[4];
  const float* bhh0    = (const float*)d_in[5];
  const float* Wih1    = (const float*)d_in[6];
  const float* Whh1    = (const float*)d_in[7];
  const float* bih1    = (const float*)d_in[8];
  const float* bhh1    = (const float*)d_in[9];
  const float* fcW     = (const float*)d_in[10];
  const float* fcb     = (const float*)d_in[11];
  float* ws = (float*)d_ws;
  float* o  = (float*)d_out;

  // zero tagged h-exchange every call (tag 0 == "initial zeros", deterministic)
  hipMemsetAsync((char*)d_ws + (size_t)OFF_HEX * 4, 0, (size_t)262144 * 4, stream);
  setup_kernel<<<3336, 256, 0, stream>>>(Wih0, Whh0, bih0, bhh0,
                                         Wih1, Whh1, bih1, bhh1, ws);
  lstm_mfma<<<256, 512, 0, stream>>>(x, targets, fcW, fcb, ws, o);
}

// Round 15
// 1476.823 us; speedup vs baseline: 1.0966x; 1.0966x over previous
//
#include <hip/hip_runtime.h>
#include <math.h>

#define BATCH  256
#define CODE   64
#define HID    256
#define TSTEPS 640     // 512 encoder + 128 decoder steps

// ---- workspace layout (float offsets)
#define OFF_A0   0          // [64rt][10f][2pl][64lane][16B bf16]  = 327680 floats
#define OFF_A1   327680     // [64rt][16f][2pl][64lane][16B bf16]  = 524288 floats
#define OFF_BP0  851968     // [1024] permuted fused bias layer0
#define OFF_BP1  852992     // [1024]
#define OFF_HEX  854016     // [2buf][16grp][16wgsrc][2layer][4uq][16b] x 16B = 1MB
#define WS_FLOATS (OFF_HEX + 524288)

typedef __attribute__((ext_vector_type(8))) short  short8;
typedef __attribute__((ext_vector_type(4))) float  f32x4;
typedef __attribute__((ext_vector_type(4))) unsigned int u32x4;
typedef __attribute__((ext_vector_type(8))) __bf16 bf16x8;
typedef unsigned long long u64;

__device__ __forceinline__ f32x4 mfma16(short8 a, short8 b, f32x4 c) {
  return __builtin_amdgcn_mfma_f32_16x16x32_bf16(
      __builtin_bit_cast(bf16x8, a), __builtin_bit_cast(bf16x8, b), c, 0, 0, 0);
}
__device__ __forceinline__ unsigned short f2bf(float f) {
  union { float f; unsigned u; } v{f};
  unsigned r = v.u + 0x7fffu + ((v.u >> 16) & 1u);   // RNE
  return (unsigned short)(r >> 16);
}
__device__ __forceinline__ float bf2f(unsigned short b) {
  union { unsigned u; float f; } v{(unsigned)b << 16};
  return v.f;
}
#define LOG2E 1.4426950408889634f
__device__ __forceinline__ float sigm(float x) {
  return __builtin_amdgcn_rcpf(1.0f + __builtin_amdgcn_exp2f(-x * LOG2E));
}
__device__ __forceinline__ float tanh_f(float x) {
  return 1.0f - 2.0f * __builtin_amdgcn_rcpf(1.0f + __builtin_amdgcn_exp2f(x * (2.0f * LOG2E)));
}

// ---- one-time weight swizzle into MFMA fragment order, hi/lo bf16 split.
__global__ void setup_kernel(const float* __restrict__ Wih0, const float* __restrict__ Whh0,
                             const float* __restrict__ bih0, const float* __restrict__ bhh0,
                             const float* __restrict__ Wih1, const float* __restrict__ Whh1,
                             const float* __restrict__ bih1, const float* __restrict__ bhh1,
                             float* __restrict__ ws) {
  int i = blockIdx.x * 256 + threadIdx.x;
  unsigned short* u = (unsigned short*)ws;
  if (i < 327680) {        // layer0: K = 320 (64 x | 256 h0)
    int rt = i / 5120, r = i % 5120;
    int f = r >> 9, l = (r >> 3) & 63, j = r & 7;
    int p = rt * 16 + (l & 15);
    int orig = (p & 3) * 256 + (p >> 2);
    int k = f * 32 + ((l >> 4) << 3) + j;
    float w = (k < 64) ? Wih0[orig * 64 + k] : Whh0[orig * 256 + k - 64];
    unsigned short hi = f2bf(w);
    unsigned short lo = f2bf(w - bf2f(hi));
    int base = OFF_A0 * 2 + (((rt * 10 + f) * 2) * 64 + l) * 8 + j;
    u[base] = hi; u[base + 512] = lo;
    return;
  }
  i -= 327680;
  if (i < 524288) {        // layer1: K = 512 (256 h0 | 256 h1)
    int rt = i >> 13, r = i & 8191;
    int f = r >> 9, l = (r >> 3) & 63, j = r & 7;
    int p = rt * 16 + (l & 15);
    int orig = (p & 3) * 256 + (p >> 2);
    int k = f * 32 + ((l >> 4) << 3) + j;
    float w = (k < 256) ? Wih1[orig * 256 + k] : Whh1[orig * 256 + k - 256];
    unsigned short hi = f2bf(w);
    unsigned short lo = f2bf(w - bf2f(hi));
    int base = OFF_A1 * 2 + (((rt * 16 + f) * 2) * 64 + l) * 8 + j;
    u[base] = hi; u[base + 512] = lo;
    return;
  }
  i -= 524288;
  if (i < 2048) {
    int layer = i >> 10, p = i & 1023;
    int orig = (p & 3) * 256 + (p >> 2);
    ws[OFF_BP0 + i] = layer ? (bih1[orig] + bhh1[orig]) : (bih0[orig] + bhh0[orig]);
  }
}

// quantum byte offset: [buf][grp][wgsrc][layer][uq][b] x 16B
// quantum = {tagA, 2 units bf16, 2 units bf16, tagB}
__device__ __forceinline__ size_t qoff(int buf, int grp, int wgsrc, int layer, int uq, int b) {
  return (size_t)(((((buf * 16 + grp) * 16 + wgsrc) * 2 + layer) * 4 + uq) * 16 + b) * 16u;
}

// ---- persistent MFMA LSTM, tagged-quantum sync (R13 = proven 1510us).
// R15 delta vs R13: double-buffered LDS frags -> ONE barrier per tick.
// compute reads parity p, poll+stage writes parity p^1; FC reads Bh1[p].
// All cross-parity -> no intra-tick hazards.
__global__ __launch_bounds__(512, 2) void lstm_mfma(
    const float* __restrict__ x, const float* __restrict__ targets,
    const float* __restrict__ fcW, const float* __restrict__ fcb,
    float* __restrict__ ws, float* __restrict__ out) {
  __shared__ __align__(16) short Bx[2][2][64][8];     // [par][xfrag]
  __shared__ __align__(16) short Bh0[2][8][64][8];    // [par][frag]
  __shared__ __align__(16) short Bh1[2][8][64][8];    // [par][frag] (FC reads too)
  __shared__ float fcw_s[64 * 257];

  const int t = threadIdx.x;
  const int blk = blockIdx.x;
  const int xcd = blk & 7, slot = blk >> 3;
  const int grp = xcd * 2 + (slot >> 4);   // 0..15
  const int wg  = slot & 15;               // 0..15

  const int w = t >> 6, l = t & 63, wl = w & 3;
  const bool isL0 = (w < 4);
  const int rt = wg * 4 + wl;

  char* hexb = (char*)(ws + OFF_HEX);

  for (int idx = t; idx < 64 * 256; idx += 512)
    fcw_s[(idx >> 8) * 257 + (idx & 255)] = fcW[idx];

  // ---- register-resident A fragments
  short8 Ah[16], Al[16];
  if (isL0) {
    const float* Ab = ws + OFF_A0 + rt * 5120;
#pragma unroll
    for (int f = 0; f < 10; ++f) {
      Ah[f] = *(const short8*)(Ab + ((f * 2 + 0) * 64 + l) * 4);
      Al[f] = *(const short8*)(Ab + ((f * 2 + 1) * 64 + l) * 4);
    }
  } else {
    const float* Ab = ws + OFF_A1 + rt * 8192;
#pragma unroll
    for (int f = 0; f < 16; ++f) {
      Ah[f] = *(const short8*)(Ab + ((f * 2 + 0) * 64 + l) * 4);
      Al[f] = *(const short8*)(Ab + ((f * 2 + 1) * 64 + l) * 4);
    }
  }
  const f32x4 bias = *(const f32x4*)(ws + (isL0 ? OFF_BP0 : OFF_BP1) + rt * 16 + ((l >> 4) << 2));
  float cst = 0.0f;

  const int col = l & 15;
  const int k0 = (w << 5) + ((l >> 4) << 3);
  const int wgsrc = k0 >> 4, uq0 = (k0 & 15) >> 2;   // uq0 in {0,2}

  // FC roles: waves 3 and 5; 2 lanes per output (k-halves), 32 outputs/wave.
  const int fc_code  = 4 * wg + ((w == 5) ? 2 : 0) + (l & 1);  // global code
  const int fc_b     = (l >> 1) & 15;                          // batch in group
  const int fc_khalf = l >> 5;                                 // 0: k<128, 1: k>=128
  const float fcb_r  = fcb[fc_code];

  float4 xr0, xr1;
  auto load_x = [&](int s) {
    if (w < 2 && s < TSTEPS) {
      const float* src;
      if (s <= 512) {
        int ss = (s < 512) ? s : 511;
        src = x + ((size_t)(grp * 16 + col) * 512 + ss) * 64 + k0;
      } else {
        src = targets + ((size_t)(grp * 16 + col) * 128 + (s - 513)) * 64 + k0;
      }
      xr0 = *(const float4*)src;
      xr1 = *(const float4*)(src + 4);
    }
  };
  auto put_x = [&](int p) {
    if (w < 2) {
      short8 v;
      v[0] = (short)f2bf(xr0.x); v[1] = (short)f2bf(xr0.y);
      v[2] = (short)f2bf(xr0.z); v[3] = (short)f2bf(xr0.w);
      v[4] = (short)f2bf(xr1.x); v[5] = (short)f2bf(xr1.y);
      v[6] = (short)f2bf(xr1.z); v[7] = (short)f2bf(xr1.w);
      *(short8*)Bx[p][w][l] = v;
    }
  };

  // ---- prologue: zero h frags (parity 0), stage x(0)
  *(u32x4*)&Bh0[0][w][l][0] = u32x4{0, 0, 0, 0};
  *(u32x4*)&Bh1[0][w][l][0] = u32x4{0, 0, 0, 0};
  load_x(0); put_x(0);
  __syncthreads();

  for (int T = 0; T <= TSTEPS + 1; ++T) {
    const int p = T & 1;

    // ---- compute phase (reads parity p)
    float hh = 0.0f;
    const bool act = isL0 ? (T < TSTEPS) : (T >= 1 && T <= TSTEPS);
    if (act) {
      f32x4 aH0 = {0.f,0.f,0.f,0.f}, aH1 = {0.f,0.f,0.f,0.f};
      f32x4 aL0 = {0.f,0.f,0.f,0.f}, aL1 = {0.f,0.f,0.f,0.f};
      if (isL0) {
        {
          short8 b0 = *(const short8*)Bx[p][0][l];
          aH0 = mfma16(Ah[0], b0, aH0); aL0 = mfma16(Al[0], b0, aL0);
          short8 b1 = *(const short8*)Bx[p][1][l];
          aH1 = mfma16(Ah[1], b1, aH1); aL1 = mfma16(Al[1], b1, aL1);
        }
#pragma unroll
        for (int f = 2; f < 10; ++f) {
          short8 b = *(const short8*)Bh0[p][f - 2][l];
          if (f & 1) { aH1 = mfma16(Ah[f], b, aH1); aL1 = mfma16(Al[f], b, aL1); }
          else       { aH0 = mfma16(Ah[f], b, aH0); aL0 = mfma16(Al[f], b, aL0); }
        }
      } else {
#pragma unroll
        for (int f = 0; f < 8; ++f) {
          short8 b = *(const short8*)Bh0[p][f][l];
          if (f & 1) { aH1 = mfma16(Ah[f], b, aH1); aL1 = mfma16(Al[f], b, aL1); }
          else       { aH0 = mfma16(Ah[f], b, aH0); aL0 = mfma16(Al[f], b, aL0); }
        }
#pragma unroll
        for (int f = 8; f < 16; ++f) {
          short8 b = *(const short8*)Bh1[p][f - 8][l];
          if (f & 1) { aH1 = mfma16(Ah[f], b, aH1); aL1 = mfma16(Al[f], b, aL1); }
          else       { aH0 = mfma16(Ah[f], b, aH0); aL0 = mfma16(Al[f], b, aL0); }
        }
      }
      f32x4 s = aH0 + aH1 + aL0 + aL1 + bias;
      cst = sigm(s.y) * cst + sigm(s.x) * tanh_f(s.z);
      hh = sigm(s.w) * tanh_f(cst);
    }

    const unsigned tag = (unsigned)(T + 1);

    // ---- export: shfl-pack 4 units x batch, single tagged 16B store (no drain)
    if (T <= TSTEPS) {
      unsigned bh = f2bf(hh);
      unsigned v0 = __shfl((int)bh, (l & 15));
      unsigned v1 = __shfl((int)bh, 16 + (l & 15));
      unsigned v2 = __shfl((int)bh, 32 + (l & 15));
      unsigned v3 = __shfl((int)bh, 48 + (l & 15));
      if (l < 16) {
        u32x4 ex = {tag, v0 | (v1 << 16), v2 | (v3 << 16), tag};
        char* pe = hexb + qoff(p, grp, wg, isL0 ? 0 : 1, wl, l);
        asm volatile("global_store_dwordx4 %0, %1, off sc0 sc1"
                     :: "v"(pe), "v"(ex) : "memory");
      }
    }

    if (w < 2 && (T + 1) < TSTEPS) load_x(T + 1);   // x prefetch into regs

    // ---- FC projection: waves 3 & 5, 2 lanes/output (k-halves), 4 chains.
    //      Reads Bh1[p] = h1(T-2); conflict-free LDS access.
    if ((w == 3 || w == 5) && T >= 514) {
      int d = T - 514;
      float a0 = 0.f, a1 = 0.f, a2 = 0.f, a3 = 0.f;
      const float* fw = fcw_s + fc_code * 257 + fc_khalf * 128;
#pragma unroll
      for (int kq = 0; kq < 4; ++kq) {
        int f = fc_khalf * 4 + kq;
        short8 h0v = *(const short8*)Bh1[p][f][0 * 16 + fc_b];
        short8 h1v = *(const short8*)Bh1[p][f][1 * 16 + fc_b];
        short8 h2v = *(const short8*)Bh1[p][f][2 * 16 + fc_b];
        short8 h3v = *(const short8*)Bh1[p][f][3 * 16 + fc_b];
#pragma unroll
        for (int j = 0; j < 8; ++j) {
          a0 = fmaf(fw[kq * 32 + j],      bf2f((unsigned short)h0v[j]), a0);
          a1 = fmaf(fw[kq * 32 + 8 + j],  bf2f((unsigned short)h1v[j]), a1);
          a2 = fmaf(fw[kq * 32 + 16 + j], bf2f((unsigned short)h2v[j]), a2);
          a3 = fmaf(fw[kq * 32 + 24 + j], bf2f((unsigned short)h3v[j]), a3);
        }
      }
      float acc = (a0 + a1) + (a2 + a3);
      acc += __shfl_xor(acc, 32);     // combine k-halves (l <-> l^32)
      if (l < 32)
        __builtin_nontemporal_store(acc + fcb_r,
            &out[(size_t)(grp * 16 + fc_b) * 8192 + d * 64 + fc_code]);
    }

    // ---- poll (fused detect+data) + stage into parity p^1
    if (T <= TSTEPS) {
      char* pb = hexb + qoff(p, grp, wgsrc, 0, uq0, col);
      u32x4 q00, q01, q10, q11;
      while (true) {
        asm volatile(
            "global_load_dwordx4 %0, %4, off sc0 sc1\n\t"
            "global_load_dwordx4 %1, %4, off offset:256 sc0 sc1\n\t"
            "global_load_dwordx4 %2, %4, off offset:1024 sc0 sc1\n\t"
            "global_load_dwordx4 %3, %4, off offset:1280 sc0 sc1\n\t"
            "s_waitcnt vmcnt(0)"
            : "=v"(q00), "=v"(q01), "=v"(q10), "=v"(q11)
            : "v"(pb) : "memory");
        bool ok = (q00.x == tag) & (q00.w == tag) & (q01.x == tag) & (q01.w == tag) &
                  (q10.x == tag) & (q10.w == tag) & (q11.x == tag) & (q11.w == tag);
        if (__all(ok)) break;
        __builtin_amdgcn_s_sleep(2);   // backoff only after a miss
      }
      *(u32x4*)&Bh0[p ^ 1][w][l][0] = u32x4{q00.y, q00.z, q01.y, q01.z};
      *(u32x4*)&Bh1[p ^ 1][w][l][0] = u32x4{q10.y, q10.z, q11.y, q11.z};
      if ((T + 1) < TSTEPS) put_x(p ^ 1);
    }
    __syncthreads();                 // single barrier: parity p^1 ready for T+1
  }
}

extern "C" void kernel_launch(void* const* d_in, const int* in_sizes, int n_in,
                              void* d_out, int out_size, void* d_ws, size_t ws_size,
                              hipStream_t stream) {
  const float* x       = (const float*)d_in[0];
  const float* targets = (const float*)d_in[1];
  const float* Wih0    = (const float*)d_in[2];
  const float* Whh0    = (const float*)d_in[3];
  const float* bih0    = (const float*)d_in[4];
  const float* bhh0    = (const float*)d_in[5];
  const float* Wih1    = (const float*)d_in[6];
  const float* Whh1    = (const float*)d_in[7];
  const float* bih1    = (const float*)d_in[8];
  const float* bhh1    = (const float*)d_in[9];
  const float* fcW     = (const float*)d_in[10];
  const float* fcb     = (const float*)d_in[11];
  float* ws = (float*)d_ws;
  float* o  = (float*)d_out;

  // zero tagged h-exchange every call (tag 0 == "initial zeros", deterministic)
  hipMemsetAsync((char*)d_ws + (size_t)OFF_HEX * 4, 0, (size_t)524288 * 4, stream);
  setup_kernel<<<3336, 256, 0, stream>>>(Wih0, Whh0, bih0, bhh0,
                                         Wih1, Whh1, bih1, bhh1, ws);
  lstm_mfma<<<256, 512, 0, stream>>>(x, targets, fcW, fcb, ws, o);
}